// Round 2
// baseline (394.731 us; speedup 1.0000x reference)
//
#include <hip/hip_runtime.h>
#include <math.h>

#define ROW_N 512
#define N_ITERS 100
#define LAMBDA 10.0f

// Precompute FISTA momentum coefficients coef[k] = (t_k - 1) / t_{k+1}.
__global__ void coef_kernel(float* __restrict__ coefs) {
    if (threadIdx.x == 0) {
        float t = 1.0f;
        for (int k = 0; k < N_ITERS; ++k) {
            float t_new = 0.5f * (1.0f + sqrtf(1.0f + 4.0f * t * t));
            coefs[k] = (t - 1.0f) / t_new;
            t = t_new;
        }
    }
}

__device__ __forceinline__ float lane_gather(int byte_addr, float v) {
    // raw ds_bpermute: no clamp code; boundary lanes are ghost-overridden anyway
    return __int_as_float(__builtin_amdgcn_ds_bpermute(byte_addr, __float_as_int(v)));
}

// ONE row per wave, scalar f32, 8 elems/lane (16384 waves, 4096 blocks).
// Rationale vs the previous 2-rows-per-wave f2 version: v_pk_*_f32 is
// half-rate on CDNA4 (packed == scalar in issue cycles), so f2 packing only
// doubled per-wave register state (~100+ VGPR -> 3.5 waves/SIMD resident,
// OccupancyPercent 44, VALUBusy 85 with ds_bpermute + s_load stalls showing
// through). Scalar state is y/ay/xA/xB/z = 40 + halos ~4 + addrs -> ~60 VGPR
// -> 8 waves/SIMD, same total issue cycles, double the latency hiding.
// Direct pentadiagonal stencil (5 ops/elem), exact boundary via ghosts:
//   z_{-1} = 2 z0 - z1, z_{-2} = 3 z0 - 2 z1   (mirrored at bottom).
// Shuffles are raw ds_bpermute on PRECOMPUTED byte addresses (kills the
// __shfl address/clamp VALU per call). Coef pair is prefetched one loop
// body (~2 steps) ahead of use so SMEM latency never heads the chain.
template <bool USE_TABLE>
__global__ __launch_bounds__(256)
__attribute__((amdgpu_waves_per_eu(4, 8)))
void fista_kernel(
    const float* __restrict__ in, float* __restrict__ out,
    const float* __restrict__ coefs, int n_rows)
{
    const int wid  = (int)((blockIdx.x * 256u + threadIdx.x) >> 6); // one row per wave
    const int lane = (int)(threadIdx.x & 63u);
    if (wid >= n_rows) return;

    const bool lane_lo = (lane == 0);
    const bool lane_hi = (lane == 63);
    const int addr_up = ((lane - 1) & 63) << 2;   // neighbor below (lane-1)
    const int addr_dn = ((lane + 1) & 63) << 2;   // neighbor above (lane+1)

    const float* row = in + (size_t)wid * ROW_N + lane * 8;

    const float A  = 1.0f / (1.0f + 16.0f * LAMBDA);   // 2*step
    const float B  = LAMBDA / (1.0f + 16.0f * LAMBDA); // 2*step*lam
    const float C  = 1.0f - A;
    const float K0 = C - 6.0f * B;   // center coeff
    const float B4 = 4.0f * B;       // +-1 neighbor coeff
    const float Bn = -B;             // +-2 neighbor coeff

    float y[8], ay[8], xA[8], xB[8], z[8];
    {
        const float4 a0 = *(const float4*)(row);
        const float4 a1 = *(const float4*)(row + 4);
        y[0] = a0.x; y[1] = a0.y; y[2] = a0.z; y[3] = a0.w;
        y[4] = a1.x; y[5] = a1.y; y[6] = a1.z; y[7] = a1.w;
    }

    // loop-carried halos: zm1/zm2 = z_{-1}/z_{-2} (ghost-selected, current
    // vintage); sp0/sp1 = RAW shuffled z0/z1 of lane+1 (ghost-selected in step)
    float zm1, zm2, sp0, sp1;

    auto upd = [&](int i, float a, float b, float c, float d,
                   const float* xin, float* xout, float cf) {
        float t1 = a + b;                        // z_{i-1} + z_{i+1} (old)
        float t2 = c + d;                        // z_{i-2} + z_{i+2} (old)
        float u  = fmaf(K0, z[i], ay[i]);
        u = fmaf(B4, t1, u);
        u = fmaf(Bn, t2, u);
        float xe = __builtin_amdgcn_fmed3f(u, 0.0f, y[i]);  // clip(u, 0, y)
        z[i] = fmaf(cf, xe - xin[i], xe);
        xout[i] = xe;
    };

    auto step = [&](const float* xin, float* xout, float cf) {
        // captures of old z needed after in-place writes (SSA renames, free)
        const float z2o = z[2], z3o = z[3], z4o = z[4], z5o = z[5];
        upd(2, z[1], z[3], z[0], z[4], xin, xout, cf);
        upd(3, z2o,  z[4], z[1], z[5], xin, xout, cf);
        upd(4, z3o,  z[5], z2o,  z[6], xin, xout, cf);
        upd(5, z4o,  z[6], z3o,  z[7], xin, xout, cf);

        // down-halo (old vintage): ghosts from old z6,z7; sp0/sp1 were issued
        // at the END of the previous step (~40 insts of slack)
        float gp0 = fmaf(2.0f, z[7], -z[6]);     // 2 z7 - z6
        float gp1 = fmaf(2.0f, gp0, -z[7]);      // 3 z7 - 2 z6
        float zp0 = lane_hi ? gp0 : sp0;
        float zp1 = lane_hi ? gp1 : sp1;

        const float z6o = z[6];
        upd(6, z5o, z[7], z4o, zp0, xin, xout, cf);
        upd(7, z6o, zp0,  z5o, zp1, xin, xout, cf);

        // up-shuffles of NEW z6,z7; consumed at end-of-step select (~20 insts)
        float um2 = lane_gather(addr_up, z[6]);
        float um1 = lane_gather(addr_up, z[7]);

        const float z0o = z[0];
        upd(0, zm1, z[1], zm2, z2o, xin, xout, cf);
        upd(1, z0o, z2o,  zm1, z3o, xin, xout, cf);

        // halos for NEXT step: ghosts from NEW z0,z1
        float gm1 = fmaf(2.0f, z[0], -z[1]);
        float gm2 = fmaf(2.0f, gm1, -z[0]);
        zm1 = lane_lo ? gm1 : um1;
        zm2 = lane_lo ? gm2 : um2;

        // down-shuffles of NEW z0,z1 (selected in NEXT step before elem 6)
        sp0 = lane_gather(addr_dn, z[0]);
        sp1 = lane_gather(addr_dn, z[1]);
    };

    #pragma unroll 1
    for (int pass = 0; pass < 2; ++pass) {
        #pragma unroll
        for (int i = 0; i < 8; ++i) {
            ay[i] = A * y[i];
            xA[i] = y[i];   // x0 = proj(y) = y  (y >= 0 by construction)
            z[i]  = y[i];
        }
        // prime halos (vintage: initial z)
        {
            float um2 = lane_gather(addr_up, z[6]);
            float um1 = lane_gather(addr_up, z[7]);
            float gm1 = fmaf(2.0f, z[0], -z[1]);
            float gm2 = fmaf(2.0f, gm1, -z[0]);
            zm1 = lane_lo ? gm1 : um1;
            zm2 = lane_lo ? gm2 : um2;
            sp0 = lane_gather(addr_dn, z[0]);
            sp1 = lane_gather(addr_dn, z[1]);
        }

        float c0, c1, tcur = 1.0f;
        if (USE_TABLE) { c0 = coefs[0]; c1 = coefs[1]; }
        else {
            float tn = 0.5f * (1.0f + sqrtf(fmaf(4.0f * tcur, tcur, 1.0f)));
            c0 = (tcur - 1.0f) / tn;
            float tn2 = 0.5f * (1.0f + sqrtf(fmaf(4.0f * tn, tn, 1.0f)));
            c1 = (tn - 1.0f) / tn2;
            tcur = tn2;
        }

        #pragma unroll 1
        for (int it = 0; it < N_ITERS; it += 2) {
            // prefetch NEXT pair at body top: s_load issues here, consumed
            // two full steps later -> SMEM latency fully hidden
            float n0, n1;
            if (USE_TABLE) {
                const int j = (it + 2 < N_ITERS) ? it + 2 : 0;
                n0 = coefs[j];
                n1 = coefs[j + 1];
            } else {
                float tn = 0.5f * (1.0f + sqrtf(fmaf(4.0f * tcur, tcur, 1.0f)));
                n0 = (tcur - 1.0f) / tn;
                float tn2 = 0.5f * (1.0f + sqrtf(fmaf(4.0f * tn, tn, 1.0f)));
                n1 = (tn - 1.0f) / tn2;
                tcur = tn2;
            }
            step(xA, xB, c0);   // reads xA as x_old, writes xB
            step(xB, xA, c1);   // N_ITERS even -> final x lands in xA
            c0 = n0; c1 = n1;
        }

        if (pass == 0) {
            #pragma unroll
            for (int i = 0; i < 8; ++i) y[i] = xA[i];  // pass 2: y = pass-1 x
        }
    }

    float* orow = out + (size_t)wid * ROW_N + lane * 8;
    *(float4*)(orow)     = make_float4(xA[0], xA[1], xA[2], xA[3]);
    *(float4*)(orow + 4) = make_float4(xA[4], xA[5], xA[6], xA[7]);
}

extern "C" void kernel_launch(void* const* d_in, const int* in_sizes, int n_in,
                              void* d_out, int out_size, void* d_ws, size_t ws_size,
                              hipStream_t stream) {
    const float* in = (const float*)d_in[0];
    float* out = (float*)d_out;

    const int total  = in_sizes[0];
    const int n_rows = total / ROW_N;            // 16384 rows, one wave each
    const int waves_per_block = 4;               // 256 threads
    const int blocks = (n_rows + waves_per_block - 1) / waves_per_block;

    if (ws_size >= N_ITERS * sizeof(float)) {
        float* coefs = (float*)d_ws;
        coef_kernel<<<1, 64, 0, stream>>>(coefs);
        fista_kernel<true><<<blocks, 256, 0, stream>>>(in, out, coefs, n_rows);
    } else {
        fista_kernel<false><<<blocks, 256, 0, stream>>>(in, out, nullptr, n_rows);
    }
}

// Round 4
// 344.812 us; speedup vs baseline: 1.1448x; 1.1448x over previous
//
#include <hip/hip_runtime.h>
#include <math.h>

#define ROW_N 512
#define N_ITERS 100
#define LAMBDA 10.0f

typedef float f2 __attribute__((ext_vector_type(2)));

__device__ __forceinline__ f2 splat(float s) { f2 r; r.x = s; r.y = s; return r; }
__device__ __forceinline__ f2 ffma(f2 a, f2 b, f2 c) {
    return __builtin_elementwise_fma(a, b, c);
}

// Full-wave DPP shift with the boundary ghost fused into the invalid-lane
// value. GCN convention (per the canonical DPP scan idiom, which uses
// row_shr:1 to accumulate from LOWER lanes):
//   wave_shr:1 (0x138): lane i <- lane i-1; lane 0 invalid  -> keeps `old`.
//   wave_shl:1 (0x130): lane i <- lane i+1; lane 63 invalid -> keeps `old`.
// (Round-3 bug: these two were swapped -> wrong neighbors AND ghost at the
// wrong end; absmax 0.887.)
// bound_ctrl=false => invalid lanes preserve `old` (our boundary ghost),
// which deletes the per-step v_cndmask selects AND moves the shuffle off
// the LDS pipe (no lgkmcnt waits) onto the VALU pipe.
#define DPP_WAVE_SHL1 0x130
#define DPP_WAVE_SHR1 0x138

template <int CTRL>
__device__ __forceinline__ f2 dpp2(f2 old, f2 src) {
    f2 r;
    r.x = __int_as_float(__builtin_amdgcn_update_dpp(
        __float_as_int(old.x), __float_as_int(src.x), CTRL, 0xF, 0xF, false));
    r.y = __int_as_float(__builtin_amdgcn_update_dpp(
        __float_as_int(old.y), __float_as_int(src.y), CTRL, 0xF, 0xF, false));
    return r;
}

// Precompute FISTA momentum coefficients coef[k] = (t_k - 1) / t_{k+1}.
__global__ void coef_kernel(float* __restrict__ coefs) {
    if (threadIdx.x == 0) {
        float t = 1.0f;
        for (int k = 0; k < N_ITERS; ++k) {
            float t_new = 0.5f * (1.0f + sqrtf(1.0f + 4.0f * t * t));
            coefs[k] = (t - 1.0f) / t_new;
            t = t_new;
        }
    }
}

// TWO rows per wave packed in f2 components (8192 waves, 2048 blocks).
// Round-2 lesson: v_pk_*_f32 is FULL-RATE on gfx950 (457 cyc/wave-iter at
// ~226 inst/iter = 2.02 cyc/inst measured), so f2 packing halves per-row
// issue cycles — the scalar 1-row/wave variant regressed (268 vs 228
// cyc/row-iter) despite 72% occupancy. This round keeps the f2 structure
// and deletes the remaining non-packed overhead: ds_bpermute + 16 cndmask
// ghost-selects per step become 8 update_dpp wave shifts with the ghost in
// the `old` operand (select fused, VALU pipe, no lgkm waits).
// Direct pentadiagonal stencil (verified exact vs D^T D rows 0,1,n-2,n-1):
//   u = ay + (C-6B) z_i + 4B (z_{i-1}+z_{i+1}) - B (z_{i-2}+z_{i+2})
//   ghosts: z_{-1} = 2 z0 - z1, z_{-2} = 3 z0 - 2 z1 (mirrored at bottom).
template <bool USE_TABLE>
__global__ __launch_bounds__(256)
__attribute__((amdgpu_waves_per_eu(2, 8)))
void fista_kernel(
    const float* __restrict__ in, float* __restrict__ out,
    const float* __restrict__ coefs, int n_rows)
{
    const int pid  = (int)((blockIdx.x * 256u + threadIdx.x) >> 6); // row pair
    const int lane = (int)(threadIdx.x & 63u);
    const int n_pairs = (n_rows + 1) >> 1;
    if (pid >= n_pairs) return;

    const int r0 = pid * 2;
    const int r1 = (r0 + 1 < n_rows) ? r0 + 1 : r0;
    const float* rowA = in + (size_t)r0 * ROW_N + lane * 8;
    const float* rowB = in + (size_t)r1 * ROW_N + lane * 8;

    const float A = 1.0f / (1.0f + 16.0f * LAMBDA);   // 2*step
    const float B = LAMBDA / (1.0f + 16.0f * LAMBDA); // 2*step*lam
    const float C = 1.0f - A;
    const f2 K0 = splat(C - 6.0f * B);  // center coeff
    const f2 B4 = splat(4.0f * B);      // +-1 neighbor coeff
    const f2 Bn = splat(-B);            // +-2 neighbor coeff
    const f2 Av = splat(A);
    const f2 TWO = splat(2.0f);

    f2 y[8], ay[8], xA[8], xB[8], z[8];
    {
        const float4 a0 = *(const float4*)(rowA);
        const float4 a1 = *(const float4*)(rowA + 4);
        const float4 b0 = *(const float4*)(rowB);
        const float4 b1 = *(const float4*)(rowB + 4);
        y[0].x = a0.x; y[1].x = a0.y; y[2].x = a0.z; y[3].x = a0.w;
        y[4].x = a1.x; y[5].x = a1.y; y[6].x = a1.z; y[7].x = a1.w;
        y[0].y = b0.x; y[1].y = b0.y; y[2].y = b0.z; y[3].y = b0.w;
        y[4].y = b1.x; y[5].y = b1.y; y[6].y = b1.z; y[7].y = b1.w;
    }

    // loop-carried halos (ghost already fused at the boundary lane):
    // zm1/zm2 = z_{-1}/z_{-2};  zp0/zp1 = z_{+8}/z_{+9}  (old vintage)
    f2 zm1, zm2, zp0, zp1;

    // end-of-step halo prep: z[] now holds the NEXT step's "old" vintage
    auto make_halos = [&]() {
        f2 gm1 = ffma(TWO, z[0], -z[1]);   // ghost z_{-1} = 2 z0 - z1
        f2 gm2 = ffma(TWO, gm1, -z[0]);    // ghost z_{-2} = 3 z0 - 2 z1
        f2 gp0 = ffma(TWO, z[7], -z[6]);   // ghost z_{n}  = 2 z7 - z6
        f2 gp1 = ffma(TWO, gp0, -z[7]);    // ghost z_{n+1}= 3 z7 - 2 z6
        // lane i-1's z7/z6 (ghost kept at lane 0): wave_shr:1
        zm1 = dpp2<DPP_WAVE_SHR1>(gm1, z[7]);
        zm2 = dpp2<DPP_WAVE_SHR1>(gm2, z[6]);
        // lane i+1's z0/z1 (ghost kept at lane 63): wave_shl:1
        zp0 = dpp2<DPP_WAVE_SHL1>(gp0, z[0]);
        zp1 = dpp2<DPP_WAVE_SHL1>(gp1, z[1]);
    };

    auto upd = [&](int i, f2 a, f2 b, f2 c, f2 d,
                   const f2* xin, f2* xout, f2 cf) {
        f2 t1 = a + b;                        // z_{i-1} + z_{i+1} (old)
        f2 t2 = c + d;                        // z_{i-2} + z_{i+2} (old)
        f2 u = ffma(K0, z[i], ay[i]);
        u = ffma(B4, t1, u);
        u = ffma(Bn, t2, u);
        f2 xe;
        xe.x = __builtin_amdgcn_fmed3f(u.x, 0.0f, y[i].x); // clip(u,0,y)
        xe.y = __builtin_amdgcn_fmed3f(u.y, 0.0f, y[i].y);
        z[i] = ffma(cf, xe - xin[i], xe);
        xout[i] = xe;
    };

    auto step = [&](const f2* xin, f2* xout, float cfs) {
        const f2 cf = splat(cfs);
        // rolling window of old z values (SSA renames under full unroll)
        f2 o0 = z[0], o1 = z[1], o2 = z[2], o3 = z[3], o4 = z[4],
           o5 = z[5], o6 = z[6];
        upd(0, zm1, z[1], zm2, z[2], xin, xout, cf);
        upd(1, o0,  z[2], zm1, z[3], xin, xout, cf);
        upd(2, o1,  z[3], o0,  z[4], xin, xout, cf);
        upd(3, o2,  z[4], o1,  z[5], xin, xout, cf);
        upd(4, o3,  z[5], o2,  z[6], xin, xout, cf);
        upd(5, o4,  z[6], o3,  z[7], xin, xout, cf);
        upd(6, o5,  z[7], o4,  zp0,  xin, xout, cf);
        upd(7, o6,  zp0,  o5,  zp1,  xin, xout, cf);
        make_halos();
    };

    #pragma unroll 1
    for (int pass = 0; pass < 2; ++pass) {
        #pragma unroll
        for (int i = 0; i < 8; ++i) {
            ay[i] = Av * y[i];
            xA[i] = y[i];   // x0 = proj(y) = y  (y >= 0 by construction)
            z[i]  = y[i];
        }
        make_halos();       // prime halos from initial z

        float c0, c1, tcur = 1.0f;
        if (USE_TABLE) { c0 = coefs[0]; c1 = coefs[1]; }
        else {
            float tn = 0.5f * (1.0f + sqrtf(fmaf(4.0f * tcur, tcur, 1.0f)));
            c0 = (tcur - 1.0f) / tn;
            float tn2 = 0.5f * (1.0f + sqrtf(fmaf(4.0f * tn, tn, 1.0f)));
            c1 = (tn - 1.0f) / tn2;
            tcur = tn2;
        }

        #pragma unroll 1
        for (int it = 0; it < N_ITERS; it += 2) {
            // prefetch NEXT coef pair; consumed two full steps later
            float n0, n1;
            if (USE_TABLE) {
                const int j = (it + 2 < N_ITERS) ? it + 2 : 0;
                n0 = coefs[j];
                n1 = coefs[j + 1];
            } else {
                float tn = 0.5f * (1.0f + sqrtf(fmaf(4.0f * tcur, tcur, 1.0f)));
                n0 = (tcur - 1.0f) / tn;
                float tn2 = 0.5f * (1.0f + sqrtf(fmaf(4.0f * tn, tn, 1.0f)));
                n1 = (tn - 1.0f) / tn2;
                tcur = tn2;
            }
            step(xA, xB, c0);   // reads xA as x_old, writes xB
            step(xB, xA, c1);   // N_ITERS even -> final x lands in xA
            c0 = n0; c1 = n1;
        }

        if (pass == 0) {
            #pragma unroll
            for (int i = 0; i < 8; ++i) y[i] = xA[i];  // pass 2: y = pass-1 x
        }
    }

    float* orowA = out + (size_t)r0 * ROW_N + lane * 8;
    *(float4*)(orowA)     = make_float4(xA[0].x, xA[1].x, xA[2].x, xA[3].x);
    *(float4*)(orowA + 4) = make_float4(xA[4].x, xA[5].x, xA[6].x, xA[7].x);
    if (r1 > r0) {
        float* orowB = out + (size_t)r1 * ROW_N + lane * 8;
        *(float4*)(orowB)     = make_float4(xA[0].y, xA[1].y, xA[2].y, xA[3].y);
        *(float4*)(orowB + 4) = make_float4(xA[4].y, xA[5].y, xA[6].y, xA[7].y);
    }
}

extern "C" void kernel_launch(void* const* d_in, const int* in_sizes, int n_in,
                              void* d_out, int out_size, void* d_ws, size_t ws_size,
                              hipStream_t stream) {
    const float* in = (const float*)d_in[0];
    float* out = (float*)d_out;

    const int total   = in_sizes[0];
    const int n_rows  = total / ROW_N;          // 16384
    const int n_pairs = (n_rows + 1) >> 1;      // 8192 waves, 1 pair/wave
    const int waves_per_block = 4;              // 256 threads
    const int blocks = (n_pairs + waves_per_block - 1) / waves_per_block;

    if (ws_size >= N_ITERS * sizeof(float)) {
        float* coefs = (float*)d_ws;
        coef_kernel<<<1, 64, 0, stream>>>(coefs);
        fista_kernel<true><<<blocks, 256, 0, stream>>>(in, out, coefs, n_rows);
    } else {
        fista_kernel<false><<<blocks, 256, 0, stream>>>(in, out, nullptr, n_rows);
    }
}